// Round 1
// baseline (62.378 us; speedup 1.0000x reference)
//
#include <hip/hip_runtime.h>
#include <math.h>

#define RG 61
#define CG 61
#define NP 3721           // RG*CG
#define NSEG 3722         // NP+1
#define NCLS 10
#define KTOT 12288        // 64*64*3
#define THRESHV 0.7f

// ---------------------------------------------------------------------------
// Kernel 1: logits + softmax + prob output + per-class mask.
// One block handles 4 adjacent patches in a row (shares W row loads 4x).
// grid = 61 * 16 blocks of 256 threads.
// ---------------------------------------------------------------------------
__global__ __launch_bounds__(256) void wod_logits(
    const float* __restrict__ img,   // (1024,1024,3)
    const float* __restrict__ W,     // (12288,10)
    const float* __restrict__ bias,  // (10)
    float* __restrict__ out_prob,    // (61,61,10)
    int* __restrict__ mask)          // (10,3721)
{
    const int tid = threadIdx.x;
    const int blk = blockIdx.x;
    const int r   = blk / 16;
    const int c0  = (blk % 16) * 4;
    const int np  = (CG - c0) < 4 ? (CG - c0) : 4;

    float acc[4][NCLS];
    #pragma unroll
    for (int p = 0; p < 4; ++p)
        #pragma unroll
        for (int k = 0; k < NCLS; ++k) acc[p][k] = 0.f;

    // element e = (i*64+j)*3+ch ; i = window row, rem = 3*j+ch in [0,192)
    for (int e = tid; e < KTOT; e += 256) {
        const int i   = e / 192;
        const int rem = e - i * 192;
        const float* wrow = W + e * NCLS;
        float w[NCLS];
        #pragma unroll
        for (int k = 0; k < NCLS; ++k) w[k] = wrow[k];
        const float* xbase = img + (16 * r + i) * 3072 + c0 * 48 + rem;
        #pragma unroll
        for (int p = 0; p < 4; ++p) {
            float x = (p < np) ? xbase[p * 48] : 0.f;
            #pragma unroll
            for (int k = 0; k < NCLS; ++k) acc[p][k] = fmaf(x, w[k], acc[p][k]);
        }
    }

    // wave-level tree reduction (width 64)
    #pragma unroll
    for (int p = 0; p < 4; ++p)
        #pragma unroll
        for (int k = 0; k < NCLS; ++k) {
            float v = acc[p][k];
            for (int off = 32; off; off >>= 1) v += __shfl_down(v, off);
            acc[p][k] = v;
        }

    __shared__ float red[4][4][NCLS];
    __shared__ float logit[4][NCLS];
    const int wave = tid >> 6, lane = tid & 63;
    if (lane == 0)
        for (int p = 0; p < 4; ++p)
            for (int k = 0; k < NCLS; ++k) red[wave][p][k] = acc[p][k];
    __syncthreads();
    if (tid < 4 * NCLS) {
        int p = tid / NCLS, k = tid - p * NCLS;
        logit[p][k] = red[0][p][k] + red[1][p][k] + red[2][p][k] + red[3][p][k]
                      + bias[k];
    }
    __syncthreads();
    if (tid < np) {
        const int p = tid, c = c0 + p;
        float m = -1e30f;
        for (int k = 0; k < NCLS; ++k) m = fmaxf(m, logit[p][k]);
        float ex[NCLS], s = 0.f;
        for (int k = 0; k < NCLS; ++k) { ex[k] = expf(logit[p][k] - m); s += ex[k]; }
        const float inv = 1.f / s;
        const int cell = r * CG + c;
        const int base = cell * NCLS;
        for (int k = 0; k < NCLS; ++k) {
            float pr = ex[k] * inv;
            out_prob[base + k] = pr;
            mask[k * NP + cell] = (pr > THRESHV) ? 1 : 0;
        }
    }
}

// ---------------------------------------------------------------------------
// Kernel 2: init per-segment box accumulators.
// ---------------------------------------------------------------------------
__global__ void wod_initbox(int* __restrict__ rminA, int* __restrict__ cminA,
                            int* __restrict__ rmaxA, int* __restrict__ cmaxA)
{
    int i = blockIdx.x * 256 + threadIdx.x;
    if (i < NCLS * NSEG) {
        rminA[i] = 0x3FFFFFFF;
        cminA[i] = 0x3FFFFFFF;
        rmaxA[i] = -1;
        cmaxA[i] = -1;
    }
}

// ---------------------------------------------------------------------------
// Kernel 3: connected components (min-label propagation, Gauss-Seidel in LDS)
// + label output + box extent atomics. One block per class.
// ---------------------------------------------------------------------------
__global__ __launch_bounds__(256) void wod_cc(
    const int* __restrict__ mask,     // (10,3721)
    float* __restrict__ out_lbl,      // (61,61,10) as float
    int* __restrict__ rminA, int* __restrict__ cminA,
    int* __restrict__ rmaxA, int* __restrict__ cmaxA)
{
    const int k = blockIdx.x;
    const int tid = threadIdx.x;
    __shared__ int lbl[NP];
    __shared__ int changed;

    const int* mk = mask + k * NP;
    for (int idx = tid; idx < NP; idx += 256)
        lbl[idx] = mk[idx] ? (idx + 1) : 0;
    if (tid == 0) changed = 0;
    __syncthreads();

    for (;;) {
        // pass
        for (int idx = tid; idx < NP; idx += 256) {
            int v = lbl[idx];
            if (v) {
                const int rr = idx / CG;
                const int cc = idx - rr * CG;
                int best = v;
                if (rr > 0)      { int n = lbl[idx - CG]; if (n && n < best) best = n; }
                if (rr < RG - 1) { int n = lbl[idx + CG]; if (n && n < best) best = n; }
                if (cc > 0)      { int n = lbl[idx - 1];  if (n && n < best) best = n; }
                if (cc < CG - 1) { int n = lbl[idx + 1];  if (n && n < best) best = n; }
                if (best < v) { lbl[idx] = best; changed = 1; }
            }
        }
        __syncthreads();
        const bool stop = (changed == 0);
        __syncthreads();           // all reads of `changed` done before reset
        if (stop) break;
        if (tid == 0) changed = 0;
        __syncthreads();
    }

    // emit labels (transposed to (r,c,k)) and box extents
    for (int idx = tid; idx < NP; idx += 256) {
        const int v = lbl[idx];
        out_lbl[idx * NCLS + k] = (float)v;
        if (v) {
            const int rr = idx / CG;
            const int cc = idx - rr * CG;
            atomicMin(&rminA[k * NSEG + v], rr);
            atomicMax(&rmaxA[k * NSEG + v], rr);
            atomicMin(&cminA[k * NSEG + v], cc);
            atomicMax(&cmaxA[k * NSEG + v], cc);
        }
    }
}

// ---------------------------------------------------------------------------
// Kernel 4: finalize boxes + valid.
// ---------------------------------------------------------------------------
__global__ void wod_final(const int* __restrict__ rminA, const int* __restrict__ cminA,
                          const int* __restrict__ rmaxA, const int* __restrict__ cmaxA,
                          float* __restrict__ out_box,   // (10,3722,4)
                          float* __restrict__ out_valid) // (10,3722)
{
    int i = blockIdx.x * 256 + threadIdx.x;
    if (i >= NCLS * NSEG) return;
    const int s = i % NSEG;
    const int rmx = rmaxA[i];
    const bool valid = (s > 0) && (rmx >= 0);
    float* bx = out_box + i * 4;
    if (valid) {
        bx[0] = (float)(rminA[i] - 1);
        bx[1] = (float)(cminA[i] - 1);
        bx[2] = (float)(rmx + 1);
        bx[3] = (float)(cmaxA[i] + 1);
    } else {
        bx[0] = -1.f; bx[1] = -1.f; bx[2] = -1.f; bx[3] = -1.f;
    }
    out_valid[i] = valid ? 1.f : 0.f;
}

// ---------------------------------------------------------------------------
extern "C" void kernel_launch(void* const* d_in, const int* in_sizes, int n_in,
                              void* d_out, int out_size, void* d_ws, size_t ws_size,
                              hipStream_t stream) {
    (void)in_sizes; (void)n_in; (void)out_size; (void)ws_size;
    const float* img = (const float*)d_in[0];
    const float* W   = (const float*)d_in[1];
    const float* b   = (const float*)d_in[2];

    float* out       = (float*)d_out;
    float* out_prob  = out;                       // 37210
    float* out_lbl   = out + 37210;               // 37210
    float* out_box   = out + 74420;               // 148880
    float* out_valid = out + 223300;              // 37220

    int* ws_i  = (int*)d_ws;
    int* mask  = ws_i;                            // 10*3721
    int* rminA = mask  + NCLS * NP;               // 10*3722 each
    int* cminA = rminA + NCLS * NSEG;
    int* rmaxA = cminA + NCLS * NSEG;
    int* cmaxA = rmaxA + NCLS * NSEG;

    hipLaunchKernelGGL(wod_logits, dim3(RG * 16), dim3(256), 0, stream,
                       img, W, b, out_prob, mask);
    hipLaunchKernelGGL(wod_initbox, dim3((NCLS * NSEG + 255) / 256), dim3(256), 0,
                       stream, rminA, cminA, rmaxA, cmaxA);
    hipLaunchKernelGGL(wod_cc, dim3(NCLS), dim3(256), 0, stream,
                       mask, out_lbl, rminA, cminA, rmaxA, cmaxA);
    hipLaunchKernelGGL(wod_final, dim3((NCLS * NSEG + 255) / 256), dim3(256), 0,
                       stream, rminA, cminA, rmaxA, cmaxA, out_box, out_valid);
}

// Round 2
// 51.111 us; speedup vs baseline: 1.2204x; 1.2204x over previous
//
#include <hip/hip_runtime.h>
#include <math.h>

#define RG 61
#define CG 61
#define NP 3721           // RG*CG
#define NSEG 3722         // NP+1
#define NCLS 10
#define KTOT 12288        // 64*64*3
#define NPATCH 8          // patches per block
#define THRESHV 0.7f
#define BIGI 0x3FFFFFFF

// ---------------------------------------------------------------------------
// Kernel 1: logits + softmax + prob output + per-class mask.
// One block handles 8 adjacent patches in a row. K processed in pairs so
// W loads are 5x float4 (80B aligned) and img loads are float2.
// grid = 61 * 8 blocks of 256 threads.
// ---------------------------------------------------------------------------
__global__ __launch_bounds__(256) void wod_logits(
    const float* __restrict__ img,   // (1024,1024,3)
    const float* __restrict__ W,     // (12288,10)
    const float* __restrict__ bias,  // (10)
    float* __restrict__ out_prob,    // (61,61,10)
    int* __restrict__ mask)          // (10,3721)
{
    const int tid = threadIdx.x;
    const int blk = blockIdx.x;
    const int r   = blk >> 3;
    const int c0  = (blk & 7) * NPATCH;
    const int np  = (CG - c0) < NPATCH ? (CG - c0) : NPATCH;

    float acc[NPATCH][NCLS];
    #pragma unroll
    for (int p = 0; p < NPATCH; ++p)
        #pragma unroll
        for (int k = 0; k < NCLS; ++k) acc[p][k] = 0.f;

    const float* imgr = img + (16 * r) * 3072 + c0 * 48;

    // pair index pi covers elements e=2*pi, 2*pi+1 ; e=(i*64+j)*3+ch,
    // i = window row, rem = 3*j+ch in [0,192)
    for (int pi = tid; pi < KTOT / 2; pi += 256) {
        const int e   = pi << 1;
        const int i   = e / 192;
        const int rem = e - i * 192;            // even
        const float* wp = W + e * NCLS;          // 80B aligned
        const float4 wa = *(const float4*)(wp);
        const float4 wb = *(const float4*)(wp + 4);
        const float4 wc = *(const float4*)(wp + 8);
        const float4 wd = *(const float4*)(wp + 12);
        const float4 we = *(const float4*)(wp + 16);
        const float w0[NCLS] = {wa.x, wa.y, wa.z, wa.w, wb.x, wb.y, wb.z, wb.w, wc.x, wc.y};
        const float w1[NCLS] = {wc.z, wc.w, wd.x, wd.y, wd.z, wd.w, we.x, we.y, we.z, we.w};
        const float* xb = imgr + i * 3072 + rem;
        #pragma unroll
        for (int p = 0; p < NPATCH; ++p) {
            const int po = (p < np ? p : 0) * 48;   // np uniform -> scalar select, no OOB
            const float2 x = *(const float2*)(xb + po);
            #pragma unroll
            for (int k = 0; k < NCLS; ++k) {
                acc[p][k] = fmaf(x.x, w0[k], acc[p][k]);
                acc[p][k] = fmaf(x.y, w1[k], acc[p][k]);
            }
        }
    }

    // wave-level tree reduction (width 64)
    #pragma unroll
    for (int p = 0; p < NPATCH; ++p)
        #pragma unroll
        for (int k = 0; k < NCLS; ++k) {
            float v = acc[p][k];
            for (int off = 32; off; off >>= 1) v += __shfl_down(v, off);
            acc[p][k] = v;
        }

    __shared__ float red[4][NPATCH][NCLS];
    __shared__ float logit[NPATCH][NCLS];
    const int wave = tid >> 6, lane = tid & 63;
    if (lane == 0)
        for (int p = 0; p < NPATCH; ++p)
            for (int k = 0; k < NCLS; ++k) red[wave][p][k] = acc[p][k];
    __syncthreads();
    if (tid < NPATCH * NCLS) {
        const int p = tid / NCLS, k = tid - p * NCLS;
        logit[p][k] = red[0][p][k] + red[1][p][k] + red[2][p][k] + red[3][p][k]
                      + bias[k];
    }
    __syncthreads();
    if (tid < np) {
        const int p = tid, c = c0 + p;
        float m = -1e30f;
        for (int k = 0; k < NCLS; ++k) m = fmaxf(m, logit[p][k]);
        float ex[NCLS], s = 0.f;
        for (int k = 0; k < NCLS; ++k) { ex[k] = expf(logit[p][k] - m); s += ex[k]; }
        const float inv = 1.f / s;
        const int cell = r * CG + c;
        const int base = cell * NCLS;
        for (int k = 0; k < NCLS; ++k) {
            const float pr = ex[k] * inv;
            out_prob[base + k] = pr;
            mask[k * NP + cell] = (pr > THRESHV) ? 1 : 0;
        }
    }
}

// ---------------------------------------------------------------------------
// Kernel 2: connected components (min-label propagation in LDS) + labels +
// boxes + valid, all fused. One block per class. Box extents via LDS atomics,
// two passes (min then max) to stay under the 64KB static LDS limit.
// ---------------------------------------------------------------------------
__global__ __launch_bounds__(256) void wod_cc(
    const int* __restrict__ mask,     // (10,3721)
    float* __restrict__ out_lbl,      // (61,61,10) as float
    float* __restrict__ out_box,      // (10,3722,4)
    float* __restrict__ out_valid)    // (10,3722)
{
    const int k = blockIdx.x;
    const int tid = threadIdx.x;
    __shared__ int lbl[NP];
    __shared__ int ext0[NSEG], ext1[NSEG];
    __shared__ int changed;

    const int* mk = mask + k * NP;
    for (int idx = tid; idx < NP; idx += 256)
        lbl[idx] = mk[idx] ? (idx + 1) : 0;
    if (tid == 0) changed = 0;
    __syncthreads();

    for (;;) {
        for (int idx = tid; idx < NP; idx += 256) {
            int v = lbl[idx];
            if (v) {
                const int rr = idx / CG;
                const int cc = idx - rr * CG;
                int best = v;
                if (rr > 0)      { int n = lbl[idx - CG]; if (n && n < best) best = n; }
                if (rr < RG - 1) { int n = lbl[idx + CG]; if (n && n < best) best = n; }
                if (cc > 0)      { int n = lbl[idx - 1];  if (n && n < best) best = n; }
                if (cc < CG - 1) { int n = lbl[idx + 1];  if (n && n < best) best = n; }
                if (best < v) { lbl[idx] = best; changed = 1; }
            }
        }
        __syncthreads();
        const bool stop = (changed == 0);
        __syncthreads();           // all reads of `changed` done before reset
        if (stop) break;
        if (tid == 0) changed = 0;
        __syncthreads();
    }

    // labels out (transposed to (r,c,k))
    for (int idx = tid; idx < NP; idx += 256)
        out_lbl[idx * NCLS + k] = (float)lbl[idx];

    float* boxk = out_box + k * NSEG * 4;
    float* valk = out_valid + k * NSEG;

    // pass 1: rmin / cmin
    for (int s = tid; s < NSEG; s += 256) { ext0[s] = BIGI; ext1[s] = BIGI; }
    __syncthreads();
    for (int idx = tid; idx < NP; idx += 256) {
        const int v = lbl[idx];
        if (v) {
            const int rr = idx / CG, cc = idx - rr * CG;
            atomicMin(&ext0[v], rr);
            atomicMin(&ext1[v], cc);
        }
    }
    __syncthreads();
    for (int s = tid; s < NSEG; s += 256) {
        const bool valid = (s > 0) && (ext0[s] != BIGI);
        boxk[s * 4 + 0] = valid ? (float)(ext0[s] - 1) : -1.f;
        boxk[s * 4 + 1] = valid ? (float)(ext1[s] - 1) : -1.f;
        valk[s] = valid ? 1.f : 0.f;
    }
    __syncthreads();

    // pass 2: rmax / cmax
    for (int s = tid; s < NSEG; s += 256) { ext0[s] = -1; ext1[s] = -1; }
    __syncthreads();
    for (int idx = tid; idx < NP; idx += 256) {
        const int v = lbl[idx];
        if (v) {
            const int rr = idx / CG, cc = idx - rr * CG;
            atomicMax(&ext0[v], rr);
            atomicMax(&ext1[v], cc);
        }
    }
    __syncthreads();
    for (int s = tid; s < NSEG; s += 256) {
        const bool valid = (s > 0) && (ext0[s] >= 0);
        boxk[s * 4 + 2] = valid ? (float)(ext0[s] + 1) : -1.f;
        boxk[s * 4 + 3] = valid ? (float)(ext1[s] + 1) : -1.f;
    }
}

// ---------------------------------------------------------------------------
extern "C" void kernel_launch(void* const* d_in, const int* in_sizes, int n_in,
                              void* d_out, int out_size, void* d_ws, size_t ws_size,
                              hipStream_t stream) {
    (void)in_sizes; (void)n_in; (void)out_size; (void)ws_size;
    const float* img = (const float*)d_in[0];
    const float* W   = (const float*)d_in[1];
    const float* b   = (const float*)d_in[2];

    float* out       = (float*)d_out;
    float* out_prob  = out;                       // 37210
    float* out_lbl   = out + 37210;               // 37210
    float* out_box   = out + 74420;               // 148880
    float* out_valid = out + 223300;              // 37220

    int* mask = (int*)d_ws;                       // 10*3721

    hipLaunchKernelGGL(wod_logits, dim3(RG * 8), dim3(256), 0, stream,
                       img, W, b, out_prob, mask);
    hipLaunchKernelGGL(wod_cc, dim3(NCLS), dim3(256), 0, stream,
                       mask, out_lbl, out_box, out_valid);
}